// Round 2
// baseline (4718.062 us; speedup 1.0000x reference)
//
#include <hip/hip_runtime.h>
#include <math.h>

#define NN 50000
#define NE 400000

#define SK(k) ((((k) >> 2) & 7) << 2)

__device__ __forceinline__ void atomAddF(float* p, float v) { unsafeAtomicAdd(p, v); }
__device__ __forceinline__ void atomAddD(double* p, double v) { unsafeAtomicAdd(p, v); }

// ---------------- zero fill ----------------
__global__ __launch_bounds__(256) void k_zero(float4* __restrict__ p, int n4) {
  int i = blockIdx.x * 256 + threadIdx.x;
  int s = gridDim.x * 256;
  for (; i < n4; i += s) p[i] = make_float4(0.f, 0.f, 0.f, 0.f);
}

// ---------------- embeddings ----------------
__global__ __launch_bounds__(256) void k_embed_h(const float* __restrict__ hf,
    const float* __restrict__ w, const float* __restrict__ b, float* __restrict__ h) {
  int i = blockIdx.x * 256 + threadIdx.x;  // one float4 of output
  if (i >= NN * 16) return;
  int n = i >> 4, c0 = (i & 15) * 4;
  float4 acc = *(const float4*)(b + c0);
  const float* row = hf + n * 6;
  #pragma unroll
  for (int k = 0; k < 6; ++k) {
    float x = row[k];
    const float4 wv = *(const float4*)(w + k * 64 + c0);
    acc.x += x * wv.x; acc.y += x * wv.y; acc.z += x * wv.z; acc.w += x * wv.w;
  }
  ((float4*)h)[i] = acc;
}

__global__ __launch_bounds__(256) void k_embed_e(const float* __restrict__ ef,
    const float* __restrict__ w, const float* __restrict__ b, float* __restrict__ e) {
  int i = blockIdx.x * 256 + threadIdx.x;  // one float4 of output
  if (i >= NE * 16) return;
  int ei = i >> 4, c0 = (i & 15) * 4;
  float r0 = 1.0f / ef[ei * 2 + 0];
  float r1 = 1.0f / ef[ei * 2 + 1];
  float4 acc = *(const float4*)(b + c0);
  const float4 w0 = *(const float4*)(w + c0);
  const float4 w1 = *(const float4*)(w + 64 + c0);
  acc.x += r0 * w0.x + r1 * w1.x;
  acc.y += r0 * w0.y + r1 * w1.y;
  acc.z += r0 * w0.z + r1 * w1.z;
  acc.w += r0 * w0.w + r1 * w1.w;
  ((float4*)e)[i] = acc;
}

// ---------------- node GEMM: out[y] = h @ W_y + b_y for y in {A,B,D,E} ----------------
// 128 nodes x 64 cols per block; h tile staged once (transposed+skewed), y-loop inside.
__global__ __launch_bounds__(256) void k_node_gemm(const float* __restrict__ h,
    const float* __restrict__ w0, const float* __restrict__ w1,
    const float* __restrict__ w2, const float* __restrict__ w3,
    const float* __restrict__ b0, const float* __restrict__ b1,
    const float* __restrict__ b2, const float* __restrict__ b3,
    float* __restrict__ out) {  // out = Ah base; Bh,Dh,Eh contiguous after
  __shared__ float lds[64 * 160 + 64 * 64];
  float* hsT = lds;
  float* wsh = lds + 64 * 160;
  int t = threadIdx.x;
  int n0 = blockIdx.x * 128;
  #pragma unroll
  for (int i = 0; i < 8; ++i) {
    int f = (t + i * 256) * 4;
    int r = f >> 6;
    int k = f & 63;
    int n = n0 + r;
    float4 v = make_float4(0.f, 0.f, 0.f, 0.f);
    if (n < NN) v = *(const float4*)(h + (size_t)n * 64 + k);
    int s = SK(k);
    hsT[(k + 0) * 160 + r + s] = v.x;
    hsT[(k + 1) * 160 + r + s] = v.y;
    hsT[(k + 2) * 160 + r + s] = v.z;
    hsT[(k + 3) * 160 + r + s] = v.w;
  }
  int cg = t & 7, rg = t >> 3;
  int cb = cg * 8;
  #pragma unroll 1
  for (int y = 0; y < 4; ++y) {
    const float* W = (y == 0) ? w0 : (y == 1) ? w1 : (y == 2) ? w2 : w3;
    const float* B = (y == 0) ? b0 : (y == 1) ? b1 : (y == 2) ? b2 : b3;
    __syncthreads();  // protect wsh from prior readers (and hsT staging on y==0)
    #pragma unroll
    for (int i = 0; i < 4; ++i)
      ((float4*)wsh)[t + i * 256] = ((const float4*)W)[t + i * 256];
    __syncthreads();
    float acc[4][8];
    #pragma unroll
    for (int r = 0; r < 4; ++r)
      #pragma unroll
      for (int j = 0; j < 8; ++j) acc[r][j] = 0.f;
    #pragma unroll 8
    for (int k = 0; k < 64; ++k) {
      float4 av = *(const float4*)&hsT[k * 160 + SK(k) + rg * 4];
      float4 wv0 = *(const float4*)&wsh[k * 64 + cb];
      float4 wv1 = *(const float4*)&wsh[k * 64 + cb + 4];
      float a[4] = {av.x, av.y, av.z, av.w};
      float w[8] = {wv0.x, wv0.y, wv0.z, wv0.w, wv1.x, wv1.y, wv1.z, wv1.w};
      #pragma unroll
      for (int r = 0; r < 4; ++r)
        #pragma unroll
        for (int j = 0; j < 8; ++j) acc[r][j] += a[r] * w[j];
    }
    float4 bv0 = *(const float4*)(B + cb);
    float4 bv1 = *(const float4*)(B + cb + 4);
    float* oy = out + (size_t)y * NN * 64;
    #pragma unroll
    for (int r = 0; r < 4; ++r) {
      int n = n0 + rg * 4 + r;
      if (n < NN) {
        *(float4*)(oy + (size_t)n * 64 + cb) =
            make_float4(acc[r][0] + bv0.x, acc[r][1] + bv0.y,
                        acc[r][2] + bv0.z, acc[r][3] + bv0.w);
        *(float4*)(oy + (size_t)n * 64 + cb + 4) =
            make_float4(acc[r][4] + bv1.x, acc[r][5] + bv1.y,
                        acc[r][6] + bv1.z, acc[r][7] + bv1.w);
      }
    }
  }
}

// ---------------- edge kernel (templated) ----------------
// PASS 1: e_hat = e@Cw+Cb + Dh[src] + Eh[dst]; sigma atomics into num/den; BN stats.
// PASS 2: recompute e_hat; e = e_in + relu(e_hat*sc+sh)  (e_in read back from LDS tile).
template <int PASS>
__global__ __launch_bounds__(256) void k_edge(const float* __restrict__ e,
    const float* __restrict__ Cw, const float* __restrict__ Cb,
    const int* __restrict__ src, const int* __restrict__ dst,
    const float* __restrict__ Bh, const float* __restrict__ Dh, const float* __restrict__ Eh,
    float* __restrict__ numb, float* __restrict__ denb,
    double* __restrict__ stats, const float* __restrict__ bnp,
    float* __restrict__ eout) {
  __shared__ float lds[64 * 160 + 64 * 64];
  float* esT = lds;
  float* cw = lds + 64 * 160;
  int t = threadIdx.x;
  int e0 = blockIdx.x * 128;
  {
    const float4* s4 = (const float4*)Cw;
    float4* d4 = (float4*)cw;
    #pragma unroll
    for (int i = 0; i < 4; ++i) d4[t + i * 256] = s4[t + i * 256];
  }
  #pragma unroll
  for (int i = 0; i < 8; ++i) {
    int f = (t + i * 256) * 4;
    int r = f >> 6;
    int k = f & 63;
    float4 v = *(const float4*)(e + (size_t)(e0 + r) * 64 + k);
    int s = SK(k);
    esT[(k + 0) * 160 + r + s] = v.x;
    esT[(k + 1) * 160 + r + s] = v.y;
    esT[(k + 2) * 160 + r + s] = v.z;
    esT[(k + 3) * 160 + r + s] = v.w;
  }
  __syncthreads();
  int cg = t & 7, rg = t >> 3;
  int cb = cg * 8;
  float acc[4][8];
  #pragma unroll
  for (int r = 0; r < 4; ++r)
    #pragma unroll
    for (int j = 0; j < 8; ++j) acc[r][j] = 0.f;
  #pragma unroll 8
  for (int k = 0; k < 64; ++k) {
    float4 av = *(const float4*)&esT[k * 160 + SK(k) + rg * 4];
    float4 wv0 = *(const float4*)&cw[k * 64 + cb];
    float4 wv1 = *(const float4*)&cw[k * 64 + cb + 4];
    float a[4] = {av.x, av.y, av.z, av.w};
    float w[8] = {wv0.x, wv0.y, wv0.z, wv0.w, wv1.x, wv1.y, wv1.z, wv1.w};
    #pragma unroll
    for (int r = 0; r < 4; ++r)
      #pragma unroll
      for (int j = 0; j < 8; ++j) acc[r][j] += a[r] * w[j];
  }
  float4 cb0 = *(const float4*)(Cb + cb);
  float4 cb1 = *(const float4*)(Cb + cb + 4);
  float cbv[8] = {cb0.x, cb0.y, cb0.z, cb0.w, cb1.x, cb1.y, cb1.z, cb1.w};
  float scv[8], shv[8];
  if (PASS == 2) {
    #pragma unroll
    for (int j = 0; j < 8; ++j) {
      scv[j] = bnp[128 + cb + j];
      shv[j] = bnp[192 + cb + j];
    }
  }
  float psum[8], psq[8];
  #pragma unroll
  for (int j = 0; j < 8; ++j) { psum[j] = 0.f; psq[j] = 0.f; }
  #pragma unroll
  for (int r = 0; r < 4; ++r) {
    int ei = e0 + rg * 4 + r;
    int sN = src[ei], dN = dst[ei];
    const float* dp = Dh + (size_t)sN * 64 + cb;
    const float* ep = Eh + (size_t)dN * 64 + cb;
    float4 d0 = *(const float4*)dp, d1 = *(const float4*)(dp + 4);
    float4 q0 = *(const float4*)ep, q1 = *(const float4*)(ep + 4);
    float dd[8] = {d0.x, d0.y, d0.z, d0.w, d1.x, d1.y, d1.z, d1.w};
    float qq[8] = {q0.x, q0.y, q0.z, q0.w, q1.x, q1.y, q1.z, q1.w};
    float ev[8];
    #pragma unroll
    for (int j = 0; j < 8; ++j) ev[j] = acc[r][j] + cbv[j] + dd[j] + qq[j];
    if (PASS == 1) {
      const float* bp = Bh + (size_t)sN * 64 + cb;
      float4 g0 = *(const float4*)bp, g1 = *(const float4*)(bp + 4);
      float gg[8] = {g0.x, g0.y, g0.z, g0.w, g1.x, g1.y, g1.z, g1.w};
      #pragma unroll
      for (int j = 0; j < 8; ++j) { psum[j] += ev[j]; psq[j] += ev[j] * ev[j]; }
      #pragma unroll
      for (int j = 0; j < 8; ++j) {
        float sg = 1.0f / (1.0f + __expf(-ev[j]));
        atomAddF(denb + (size_t)dN * 64 + cb + j, sg);
        atomAddF(numb + (size_t)dN * 64 + cb + j, sg * gg[j]);
      }
    } else {
      int row = rg * 4 + r;
      float ov[8];
      #pragma unroll
      for (int j = 0; j < 8; ++j) {
        int c = cb + j;
        float ein = esT[c * 160 + row + SK(c)];
        ov[j] = ein + fmaxf(ev[j] * scv[j] + shv[j], 0.f);
      }
      *(float4*)(eout + (size_t)ei * 64 + cb) = make_float4(ov[0], ov[1], ov[2], ov[3]);
      *(float4*)(eout + (size_t)ei * 64 + cb + 4) = make_float4(ov[4], ov[5], ov[6], ov[7]);
    }
  }
  if (PASS == 1) {
    __syncthreads();  // compute done; reuse lds for stats reduce
    #pragma unroll
    for (int j = 0; j < 8; ++j) {
      lds[rg * 65 + cb + j] = psum[j];
      lds[2112 + rg * 65 + cb + j] = psq[j];
    }
    __syncthreads();
    if (t < 64) {
      float s = 0.f, q = 0.f;
      #pragma unroll
      for (int i = 0; i < 32; ++i) { s += lds[i * 65 + t]; q += lds[2112 + i * 65 + t]; }
      atomAddD(stats + 128 + t, (double)s);
      atomAddD(stats + 192 + t, (double)q);
    }
  }
}

// ---------------- h_new = Ah + num/(den+1e-6) (in place), h BN stats ----------------
__global__ __launch_bounds__(256) void k_node_upd1(float* __restrict__ hn,
    const float* __restrict__ numb, const float* __restrict__ denb, double* __restrict__ stats) {
  int t = threadIdx.x;
  float psum = 0.f, psq = 0.f;
  for (int i = blockIdx.x * 256 + t; i < NN * 64; i += gridDim.x * 256) {
    float v = hn[i] + numb[i] / (denb[i] + 1e-6f);
    hn[i] = v;
    psum += v; psq += v * v;
  }
  __shared__ float red[256];
  red[t] = psum; __syncthreads();
  if (t < 64) atomAddD(stats + t, (double)(red[t] + red[t + 64] + red[t + 128] + red[t + 192]));
  __syncthreads();
  red[t] = psq; __syncthreads();
  if (t < 64) atomAddD(stats + 64 + t, (double)(red[t] + red[t + 64] + red[t + 128] + red[t + 192]));
}

// ---------------- finalize BN scale/shift ----------------
__global__ void k_bn_final(const double* __restrict__ stats,
    const float* __restrict__ hgam, const float* __restrict__ hbet,
    const float* __restrict__ egam, const float* __restrict__ ebet,
    float* __restrict__ bnp) {
  int t = threadIdx.x;
  if (t < 64) {
    double mu = stats[t] * (1.0 / NN);
    double var = stats[64 + t] * (1.0 / NN) - mu * mu;
    float sc = hgam[t] / sqrtf((float)var + 1e-5f);
    bnp[t] = sc;
    bnp[64 + t] = hbet[t] - (float)mu * sc;
  } else if (t < 128) {
    int c = t - 64;
    double mu = stats[128 + c] * (1.0 / NE);
    double var = stats[192 + c] * (1.0 / NE) - mu * mu;
    float sc = egam[c] / sqrtf((float)var + 1e-5f);
    bnp[128 + c] = sc;
    bnp[192 + c] = ebet[c] - (float)mu * sc;
  }
}

// ---------------- x = x + relu(xhat*scale + shift) ----------------
__global__ __launch_bounds__(256) void k_resid(float* __restrict__ x, const float* __restrict__ xh,
    const float* __restrict__ sc, const float* __restrict__ sh, int total4) {
  for (int i = blockIdx.x * 256 + threadIdx.x; i < total4; i += gridDim.x * 256) {
    int c = (i << 2) & 63;
    float4 hv = ((const float4*)xh)[i];
    float4 s4 = *(const float4*)(sc + c);
    float4 b4 = *(const float4*)(sh + c);
    float4 xv = ((float4*)x)[i];
    xv.x += fmaxf(hv.x * s4.x + b4.x, 0.f);
    xv.y += fmaxf(hv.y * s4.y + b4.y, 0.f);
    xv.z += fmaxf(hv.z * s4.z + b4.z, 0.f);
    xv.w += fmaxf(hv.w * s4.w + b4.w, 0.f);
    ((float4*)x)[i] = xv;
  }
}

// ---------------- per-graph mean readout (graph_ids sorted) ----------------
__global__ __launch_bounds__(256) void k_readout(const float* __restrict__ h, const int* __restrict__ gid,
    float* __restrict__ hg, float* __restrict__ counts) {
  int t = threadIdx.x;
  int c = t & 63;
  int ro = t >> 6;
  int nbase = blockIdx.x * 64;
  float sum = 0.f, cnt = 0.f;
  int curg = -1;
  #pragma unroll 1
  for (int i = 0; i < 16; ++i) {
    int n = nbase + ro + i * 4;
    if (n >= NN) break;
    int g = gid[n];
    if (g != curg) {
      if (curg >= 0) {
        atomAddF(&hg[curg * 64 + c], sum);
        if (c == 0) atomAddF(&counts[curg], cnt);
      }
      curg = g; sum = 0.f; cnt = 0.f;
    }
    sum += h[(size_t)n * 64 + c];
    cnt += 1.f;
  }
  if (curg >= 0) {
    atomAddF(&hg[curg * 64 + c], sum);
    if (c == 0) atomAddF(&counts[curg], cnt);
  }
}

// ---------------- final MLP (16 graphs), one block ----------------
__global__ __launch_bounds__(256) void k_mlp(const float* __restrict__ hg, const float* __restrict__ counts,
    const float* __restrict__ state,
    const float* __restrict__ w1, const float* __restrict__ b1,
    const float* __restrict__ w2, const float* __restrict__ b2,
    const float* __restrict__ w3, const float* __restrict__ b3,
    float* __restrict__ out) {
  __shared__ float x0[16][68];
  __shared__ float x1[16][256];
  __shared__ float x2[16][256];
  int t = threadIdx.x;
  for (int idx = t; idx < 16 * 68; idx += 256) {
    int g = idx / 68, c = idx % 68;
    x0[g][c] = (c < 64) ? hg[g * 64 + c] / counts[g] : state[g * 4 + (c - 64)];
  }
  __syncthreads();
  {
    float acc[16];
    float bb = b1[t];
    #pragma unroll
    for (int g = 0; g < 16; ++g) acc[g] = bb;
    for (int k = 0; k < 68; ++k) {
      float w = w1[k * 256 + t];
      #pragma unroll
      for (int g = 0; g < 16; ++g) acc[g] += x0[g][k] * w;
    }
    #pragma unroll
    for (int g = 0; g < 16; ++g) x1[g][t] = fmaxf(acc[g], 0.f);
  }
  __syncthreads();
  {
    float acc[16];
    float bb = b2[t];
    #pragma unroll
    for (int g = 0; g < 16; ++g) acc[g] = bb;
    for (int k = 0; k < 256; ++k) {
      float w = w2[k * 256 + t];
      #pragma unroll
      for (int g = 0; g < 16; ++g) acc[g] += x1[g][k] * w;
    }
    #pragma unroll
    for (int g = 0; g < 16; ++g) x2[g][t] = fmaxf(acc[g], 0.f);
  }
  __syncthreads();
  if (t < 32) {
    int g = t >> 1, o = t & 1;
    float acc = b3[o];
    for (int k = 0; k < 256; ++k) acc += x2[g][k] * w3[k * 2 + o];
    out[g * 2 + o] = tanhf(acc);
  }
}

extern "C" void kernel_launch(void* const* d_in, const int* in_sizes, int n_in,
                              void* d_out, int out_size, void* d_ws, size_t ws_size,
                              hipStream_t stream) {
  const float* state   = (const float*)d_in[0];
  const float* h_feat  = (const float*)d_in[1];
  const float* e_feat  = (const float*)d_in[2];
  const int*   src     = (const int*)d_in[3];
  const int*   dst     = (const int*)d_in[4];
  const int*   gid     = (const int*)d_in[5];
  const float* emb_h_w = (const float*)d_in[6];
  const float* emb_h_b = (const float*)d_in[7];
  const float* emb_e_w = (const float*)d_in[8];
  const float* emb_e_b = (const float*)d_in[9];
  const float* A_w = (const float*)d_in[10];
  const float* A_b = (const float*)d_in[11];
  const float* B_w = (const float*)d_in[12];
  const float* B_b = (const float*)d_in[13];
  const float* C_w = (const float*)d_in[14];
  const float* C_b = (const float*)d_in[15];
  const float* D_w = (const float*)d_in[16];
  const float* D_b = (const float*)d_in[17];
  const float* E_w = (const float*)d_in[18];
  const float* E_b = (const float*)d_in[19];
  const float* bn_h_g = (const float*)d_in[20];
  const float* bn_h_b = (const float*)d_in[21];
  const float* bn_e_g = (const float*)d_in[22];
  const float* bn_e_b = (const float*)d_in[23];
  const float* l1_w = (const float*)d_in[24];
  const float* l1_b = (const float*)d_in[25];
  const float* l2_w = (const float*)d_in[26];
  const float* l2_b = (const float*)d_in[27];
  const float* l3_w = (const float*)d_in[28];
  const float* l3_b = (const float*)d_in[29];

  // workspace layout (floats): total = 7*NN*64 + NE*64 + 1808  ->  ~183.1 MiB
  const size_t needF = (size_t)NN * 64 * 7 + (size_t)NE * 64 + 4096;
  if (ws_size < needF * sizeof(float)) return;  // clean failure instead of fault

  float* wsp = (float*)d_ws;
  float*  h      = wsp;                         // NN*64
  float*  e      = h + (size_t)NN * 64;         // NE*64
  float*  Ah     = e + (size_t)NE * 64;         // NN*64 (becomes h_new)
  float*  Bh     = Ah + (size_t)NN * 64;
  float*  Dh     = Bh + (size_t)NN * 64;
  float*  Eh     = Dh + (size_t)NN * 64;
  float*  numb   = Eh + (size_t)NN * 64;        // NN*64
  float*  denb   = numb + (size_t)NN * 64;      // NN*64
  double* stats  = (double*)(denb + (size_t)NN * 64);  // 256 doubles (8B-aligned)
  float*  bnp    = (float*)(stats + 256);       // 256
  float*  hg     = bnp + 256;                   // 16*64
  float*  counts = hg + 1024;                   // 16

  k_embed_h<<<(NN * 16 + 255) / 256, 256, 0, stream>>>(h_feat, emb_h_w, emb_h_b, h);
  k_embed_e<<<(NE * 16 + 255) / 256, 256, 0, stream>>>(e_feat, emb_e_w, emb_e_b, e);
  for (int l = 0; l < 3; ++l) {
    // zero numb + denb + stats (contiguous): 2*NN*64 floats + 256 doubles
    k_zero<<<2048, 256, 0, stream>>>((float4*)numb, (2 * NN * 64 + 512) / 4);
    k_node_gemm<<<(NN + 127) / 128, 256, 0, stream>>>(h,
        A_w + l * 4096, B_w + l * 4096, D_w + l * 4096, E_w + l * 4096,
        A_b + l * 64, B_b + l * 64, D_b + l * 64, E_b + l * 64, Ah);
    k_edge<1><<<NE / 128, 256, 0, stream>>>(e, C_w + l * 4096, C_b + l * 64, src, dst,
        Bh, Dh, Eh, numb, denb, stats, nullptr, nullptr);
    k_node_upd1<<<1024, 256, 0, stream>>>(Ah, numb, denb, stats);
    k_bn_final<<<1, 128, 0, stream>>>(stats, bn_h_g + l * 64, bn_h_b + l * 64,
        bn_e_g + l * 64, bn_e_b + l * 64, bnp);
    k_edge<2><<<NE / 128, 256, 0, stream>>>(e, C_w + l * 4096, C_b + l * 64, src, dst,
        Bh, Dh, Eh, numb, denb, stats, bnp, e);
    k_resid<<<512, 256, 0, stream>>>(h, Ah, bnp, bnp + 64, NN * 16);
  }
  k_zero<<<2, 256, 0, stream>>>((float4*)hg, (1024 + 16) / 4);
  k_readout<<<(NN + 63) / 64, 256, 0, stream>>>(h, gid, hg, counts);
  k_mlp<<<1, 256, 0, stream>>>(hg, counts, state,
      l1_w, l1_b, l2_w, l2_b, l3_w, l3_b, (float*)d_out);
}

// Round 4
// 1195.495 us; speedup vs baseline: 3.9465x; 3.9465x over previous
//
#include <hip/hip_runtime.h>
#include <hip/hip_fp16.h>
#include <math.h>
#include <string.h>

#define NN 50000
#define NE 400000

#define SK(k) ((((k) >> 2) & 7) << 2)

__device__ __forceinline__ void atomAddF(float* p, float v) { unsafeAtomicAdd(p, v); }
__device__ __forceinline__ void atomAddD(double* p, double v) { unsafeAtomicAdd(p, v); }
__device__ __forceinline__ int atomAddI(int* p, int v) { return atomicAdd(p, v); }

__device__ __forceinline__ unsigned pk2h(float a, float b) {
  __half2 h = __floats2half2_rn(a, b);
  unsigned v; memcpy(&v, &h, 4); return v;
}
__device__ __forceinline__ float2 up2h(unsigned v) {
  __half2 h; memcpy(&h, &v, 4); return __half22float2(h);
}

// ---------------- zero fill ----------------
__global__ __launch_bounds__(256) void k_zero(float4* __restrict__ p, int n4) {
  int i = blockIdx.x * 256 + threadIdx.x;
  int s = gridDim.x * 256;
  for (; i < n4; i += s) p[i] = make_float4(0.f, 0.f, 0.f, 0.f);
}

// ---------------- embeddings ----------------
__global__ __launch_bounds__(256) void k_embed_h(const float* __restrict__ hf,
    const float* __restrict__ w, const float* __restrict__ b, float* __restrict__ h) {
  int i = blockIdx.x * 256 + threadIdx.x;
  if (i >= NN * 16) return;
  int n = i >> 4, c0 = (i & 15) * 4;
  float4 acc = *(const float4*)(b + c0);
  const float* row = hf + n * 6;
  #pragma unroll
  for (int k = 0; k < 6; ++k) {
    float x = row[k];
    const float4 wv = *(const float4*)(w + k * 64 + c0);
    acc.x += x * wv.x; acc.y += x * wv.y; acc.z += x * wv.z; acc.w += x * wv.w;
  }
  ((float4*)h)[i] = acc;
}

__global__ __launch_bounds__(256) void k_embed_e(const float* __restrict__ ef,
    const float* __restrict__ w, const float* __restrict__ b, float* __restrict__ e) {
  int i = blockIdx.x * 256 + threadIdx.x;
  if (i >= NE * 16) return;
  int ei = i >> 4, c0 = (i & 15) * 4;
  float r0 = 1.0f / ef[ei * 2 + 0];
  float r1 = 1.0f / ef[ei * 2 + 1];
  float4 acc = *(const float4*)(b + c0);
  const float4 w0 = *(const float4*)(w + c0);
  const float4 w1 = *(const float4*)(w + 64 + c0);
  acc.x += r0 * w0.x + r1 * w1.x;
  acc.y += r0 * w0.y + r1 * w1.y;
  acc.z += r0 * w0.z + r1 * w1.z;
  acc.w += r0 * w0.w + r1 * w1.w;
  ((float4*)e)[i] = acc;
}

// ---------------- node GEMM: out[y] = h @ W_y + b_y for y in {A,B,D,E} ----------------
__global__ __launch_bounds__(256) void k_node_gemm(const float* __restrict__ h,
    const float* __restrict__ w0, const float* __restrict__ w1,
    const float* __restrict__ w2, const float* __restrict__ w3,
    const float* __restrict__ b0, const float* __restrict__ b1,
    const float* __restrict__ b2, const float* __restrict__ b3,
    float* __restrict__ out) {
  __shared__ float lds[64 * 160 + 64 * 64];
  float* hsT = lds;
  float* wsh = lds + 64 * 160;
  int t = threadIdx.x;
  int n0 = blockIdx.x * 128;
  #pragma unroll
  for (int i = 0; i < 8; ++i) {
    int f = (t + i * 256) * 4;
    int r = f >> 6;
    int k = f & 63;
    int n = n0 + r;
    float4 v = make_float4(0.f, 0.f, 0.f, 0.f);
    if (n < NN) v = *(const float4*)(h + (size_t)n * 64 + k);
    int s = SK(k);
    hsT[(k + 0) * 160 + r + s] = v.x;
    hsT[(k + 1) * 160 + r + s] = v.y;
    hsT[(k + 2) * 160 + r + s] = v.z;
    hsT[(k + 3) * 160 + r + s] = v.w;
  }
  int cg = t & 7, rg = t >> 3;
  int cb = cg * 8;
  #pragma unroll 1
  for (int y = 0; y < 4; ++y) {
    const float* W = (y == 0) ? w0 : (y == 1) ? w1 : (y == 2) ? w2 : w3;
    const float* B = (y == 0) ? b0 : (y == 1) ? b1 : (y == 2) ? b2 : b3;
    __syncthreads();
    #pragma unroll
    for (int i = 0; i < 4; ++i)
      ((float4*)wsh)[t + i * 256] = ((const float4*)W)[t + i * 256];
    __syncthreads();
    float acc[4][8];
    #pragma unroll
    for (int r = 0; r < 4; ++r)
      #pragma unroll
      for (int j = 0; j < 8; ++j) acc[r][j] = 0.f;
    #pragma unroll 8
    for (int k = 0; k < 64; ++k) {
      float4 av = *(const float4*)&hsT[k * 160 + SK(k) + rg * 4];
      float4 wv0 = *(const float4*)&wsh[k * 64 + cb];
      float4 wv1 = *(const float4*)&wsh[k * 64 + cb + 4];
      float a[4] = {av.x, av.y, av.z, av.w};
      float w[8] = {wv0.x, wv0.y, wv0.z, wv0.w, wv1.x, wv1.y, wv1.z, wv1.w};
      #pragma unroll
      for (int r = 0; r < 4; ++r)
        #pragma unroll
        for (int j = 0; j < 8; ++j) acc[r][j] += a[r] * w[j];
    }
    float4 bv0 = *(const float4*)(B + cb);
    float4 bv1 = *(const float4*)(B + cb + 4);
    float* oy = out + (size_t)y * NN * 64;
    #pragma unroll
    for (int r = 0; r < 4; ++r) {
      int n = n0 + rg * 4 + r;
      if (n < NN) {
        *(float4*)(oy + (size_t)n * 64 + cb) =
            make_float4(acc[r][0] + bv0.x, acc[r][1] + bv0.y,
                        acc[r][2] + bv0.z, acc[r][3] + bv0.w);
        *(float4*)(oy + (size_t)n * 64 + cb + 4) =
            make_float4(acc[r][4] + bv1.x, acc[r][5] + bv1.y,
                        acc[r][6] + bv1.z, acc[r][7] + bv1.w);
      }
    }
  }
}

// ================= CSR PATH kernels =================

// edge pass: e_hat = e@Cw+Cb + Dh[src] + Eh[dst]; store fp16 e_hat; exact e-BN stats.
__global__ __launch_bounds__(256) void k_edge_csr(const float* __restrict__ e,
    const float* __restrict__ Cw, const float* __restrict__ Cb,
    const int* __restrict__ src, const int* __restrict__ dst,
    const float* __restrict__ Dh, const float* __restrict__ Eh,
    __half* __restrict__ eh16, double* __restrict__ stats) {
  __shared__ float lds[64 * 160 + 64 * 64];
  float* esT = lds;
  float* cw = lds + 64 * 160;
  int t = threadIdx.x;
  int e0 = blockIdx.x * 128;
  {
    const float4* s4 = (const float4*)Cw;
    float4* d4 = (float4*)cw;
    #pragma unroll
    for (int i = 0; i < 4; ++i) d4[t + i * 256] = s4[t + i * 256];
  }
  #pragma unroll
  for (int i = 0; i < 8; ++i) {
    int f = (t + i * 256) * 4;
    int r = f >> 6;
    int k = f & 63;
    float4 v = *(const float4*)(e + (size_t)(e0 + r) * 64 + k);
    int s = SK(k);
    esT[(k + 0) * 160 + r + s] = v.x;
    esT[(k + 1) * 160 + r + s] = v.y;
    esT[(k + 2) * 160 + r + s] = v.z;
    esT[(k + 3) * 160 + r + s] = v.w;
  }
  __syncthreads();
  int cg = t & 7, rg = t >> 3;
  int cb = cg * 8;
  float acc[4][8];
  #pragma unroll
  for (int r = 0; r < 4; ++r)
    #pragma unroll
    for (int j = 0; j < 8; ++j) acc[r][j] = 0.f;
  #pragma unroll 8
  for (int k = 0; k < 64; ++k) {
    float4 av = *(const float4*)&esT[k * 160 + SK(k) + rg * 4];
    float4 wv0 = *(const float4*)&cw[k * 64 + cb];
    float4 wv1 = *(const float4*)&cw[k * 64 + cb + 4];
    float a[4] = {av.x, av.y, av.z, av.w};
    float w[8] = {wv0.x, wv0.y, wv0.z, wv0.w, wv1.x, wv1.y, wv1.z, wv1.w};
    #pragma unroll
    for (int r = 0; r < 4; ++r)
      #pragma unroll
      for (int j = 0; j < 8; ++j) acc[r][j] += a[r] * w[j];
  }
  float4 cb0 = *(const float4*)(Cb + cb);
  float4 cb1 = *(const float4*)(Cb + cb + 4);
  float cbv[8] = {cb0.x, cb0.y, cb0.z, cb0.w, cb1.x, cb1.y, cb1.z, cb1.w};
  float psum[8], psq[8];
  #pragma unroll
  for (int j = 0; j < 8; ++j) { psum[j] = 0.f; psq[j] = 0.f; }
  #pragma unroll
  for (int r = 0; r < 4; ++r) {
    int ei = e0 + rg * 4 + r;
    int sN = src[ei], dN = dst[ei];
    const float* dp = Dh + (size_t)sN * 64 + cb;
    const float* ep = Eh + (size_t)dN * 64 + cb;
    float4 d0 = *(const float4*)dp, d1 = *(const float4*)(dp + 4);
    float4 q0 = *(const float4*)ep, q1 = *(const float4*)(ep + 4);
    float dd[8] = {d0.x, d0.y, d0.z, d0.w, d1.x, d1.y, d1.z, d1.w};
    float qq[8] = {q0.x, q0.y, q0.z, q0.w, q1.x, q1.y, q1.z, q1.w};
    float ev[8];
    #pragma unroll
    for (int j = 0; j < 8; ++j) {
      float v = acc[r][j] + cbv[j] + dd[j] + qq[j];
      ev[j] = v; psum[j] += v; psq[j] += v * v;
    }
    uint4 u;
    u.x = pk2h(ev[0], ev[1]);
    u.y = pk2h(ev[2], ev[3]);
    u.z = pk2h(ev[4], ev[5]);
    u.w = pk2h(ev[6], ev[7]);
    *(uint4*)(eh16 + (size_t)ei * 64 + cb) = u;
  }
  __syncthreads();
  #pragma unroll
  for (int j = 0; j < 8; ++j) {
    lds[rg * 65 + cb + j] = psum[j];
    lds[2112 + rg * 65 + cb + j] = psq[j];
  }
  __syncthreads();
  if (t < 64) {
    float s = 0.f, q = 0.f;
    #pragma unroll
    for (int i = 0; i < 32; ++i) { s += lds[i * 65 + t]; q += lds[2112 + i * 65 + t]; }
    atomAddD(stats + 128 + t, (double)s);
    atomAddD(stats + 192 + t, (double)q);
  }
}

// CSR build
__global__ __launch_bounds__(256) void k_deg(const int* __restrict__ dst, int* __restrict__ deg) {
  int i = blockIdx.x * 256 + threadIdx.x;
  if (i < NE) atomAddI(&deg[dst[i]], 1);
}

__global__ __launch_bounds__(1024) void k_scan(const int* __restrict__ deg,
    int* __restrict__ offs, int* __restrict__ cursor) {
  __shared__ int buf[1024];
  int t = threadIdx.x;
  int carry = 0;
  for (int base = 0; base < NN; base += 1024) {
    int i = base + t;
    int v = (i < NN) ? deg[i] : 0;
    buf[t] = v;
    __syncthreads();
    for (int off = 1; off < 1024; off <<= 1) {
      int x = (t >= off) ? buf[t - off] : 0;
      __syncthreads();
      buf[t] += x;
      __syncthreads();
    }
    int excl = buf[t] - v;
    if (i < NN) { offs[i] = carry + excl; cursor[i] = carry + excl; }
    carry += buf[1023];
    __syncthreads();
  }
  if (t == 0) offs[NN] = carry;
}

__global__ __launch_bounds__(256) void k_scatter(const int* __restrict__ dst,
    const int* __restrict__ src, int* __restrict__ cursor,
    int* __restrict__ perm, int* __restrict__ srcp) {
  int i = blockIdx.x * 256 + threadIdx.x;
  if (i < NE) {
    int p = atomAddI(&cursor[dst[i]], 1);
    perm[p] = i;
    srcp[p] = src[i];
  }
}

// aggregation + h update + h BN stats (atomic-free feature aggregation)
__global__ __launch_bounds__(256) void k_agg(const int* __restrict__ offs,
    const int* __restrict__ perm, const int* __restrict__ srcp,
    const __half* __restrict__ eh16, const float* __restrict__ Bh,
    float* __restrict__ Ah, double* __restrict__ stats) {
  int t = threadIdx.x;
  int c = t & 63;
  int g = t >> 6;
  float psum = 0.f, psq = 0.f;
  #pragma unroll 1
  for (int sub = 0; sub < 4; ++sub) {
    int n = blockIdx.x * 16 + g * 4 + sub;
    if (n < NN) {
      int i0 = offs[n], i1 = offs[n + 1];
      float num = 0.f, den = 0.f;
      #pragma unroll 1
      for (int i = i0; i < i1; ++i) {
        int eid = perm[i];
        int sp = srcp[i];
        float x = __half2float(eh16[(size_t)eid * 64 + c]);
        float bh = Bh[(size_t)sp * 64 + c];
        float s = 1.0f / (1.0f + __expf(-x));
        num += s * bh;
        den += s;
      }
      float v = Ah[(size_t)n * 64 + c] + num / (den + 1e-6f);
      Ah[(size_t)n * 64 + c] = v;
      psum += v; psq += v * v;
    }
  }
  __shared__ float red[256];
  red[t] = psum; __syncthreads();
  if (t < 64) atomAddD(stats + t, (double)(red[t] + red[t + 64] + red[t + 128] + red[t + 192]));
  __syncthreads();
  red[t] = psq; __syncthreads();
  if (t < 64) atomAddD(stats + 64 + t, (double)(red[t] + red[t + 64] + red[t + 128] + red[t + 192]));
}

// e += relu(ehat16 * sc + sh), streaming
__global__ __launch_bounds__(256) void k_eresid(float* __restrict__ e,
    const __half* __restrict__ eh16, const float* __restrict__ bnp) {
  int i = blockIdx.x * 256 + threadIdx.x;  // one group of 8 cols
  if (i >= NE * 8) return;
  int c0 = (i & 7) * 8;
  uint4 u = ((const uint4*)eh16)[i];
  float2 f0 = up2h(u.x), f1 = up2h(u.y), f2 = up2h(u.z), f3 = up2h(u.w);
  float4 s0 = *(const float4*)(bnp + 128 + c0);
  float4 s1 = *(const float4*)(bnp + 128 + c0 + 4);
  float4 b0 = *(const float4*)(bnp + 192 + c0);
  float4 b1 = *(const float4*)(bnp + 192 + c0 + 4);
  float4 e0 = ((float4*)e)[i * 2];
  float4 e1 = ((float4*)e)[i * 2 + 1];
  e0.x += fmaxf(f0.x * s0.x + b0.x, 0.f);
  e0.y += fmaxf(f0.y * s0.y + b0.y, 0.f);
  e0.z += fmaxf(f1.x * s0.z + b0.z, 0.f);
  e0.w += fmaxf(f1.y * s0.w + b0.w, 0.f);
  e1.x += fmaxf(f2.x * s1.x + b1.x, 0.f);
  e1.y += fmaxf(f2.y * s1.y + b1.y, 0.f);
  e1.z += fmaxf(f3.x * s1.z + b1.z, 0.f);
  e1.w += fmaxf(f3.y * s1.w + b1.w, 0.f);
  ((float4*)e)[i * 2] = e0;
  ((float4*)e)[i * 2 + 1] = e1;
}

// ================= FALLBACK PATH kernels (round-2, known-good) =================

template <int PASS>
__global__ __launch_bounds__(256) void k_edge(const float* __restrict__ e,
    const float* __restrict__ Cw, const float* __restrict__ Cb,
    const int* __restrict__ src, const int* __restrict__ dst,
    const float* __restrict__ Bh, const float* __restrict__ Dh, const float* __restrict__ Eh,
    float* __restrict__ numb, float* __restrict__ denb,
    double* __restrict__ stats, const float* __restrict__ bnp,
    float* __restrict__ eout) {
  __shared__ float lds[64 * 160 + 64 * 64];
  float* esT = lds;
  float* cw = lds + 64 * 160;
  int t = threadIdx.x;
  int e0 = blockIdx.x * 128;
  {
    const float4* s4 = (const float4*)Cw;
    float4* d4 = (float4*)cw;
    #pragma unroll
    for (int i = 0; i < 4; ++i) d4[t + i * 256] = s4[t + i * 256];
  }
  #pragma unroll
  for (int i = 0; i < 8; ++i) {
    int f = (t + i * 256) * 4;
    int r = f >> 6;
    int k = f & 63;
    float4 v = *(const float4*)(e + (size_t)(e0 + r) * 64 + k);
    int s = SK(k);
    esT[(k + 0) * 160 + r + s] = v.x;
    esT[(k + 1) * 160 + r + s] = v.y;
    esT[(k + 2) * 160 + r + s] = v.z;
    esT[(k + 3) * 160 + r + s] = v.w;
  }
  __syncthreads();
  int cg = t & 7, rg = t >> 3;
  int cb = cg * 8;
  float acc[4][8];
  #pragma unroll
  for (int r = 0; r < 4; ++r)
    #pragma unroll
    for (int j = 0; j < 8; ++j) acc[r][j] = 0.f;
  #pragma unroll 8
  for (int k = 0; k < 64; ++k) {
    float4 av = *(const float4*)&esT[k * 160 + SK(k) + rg * 4];
    float4 wv0 = *(const float4*)&cw[k * 64 + cb];
    float4 wv1 = *(const float4*)&cw[k * 64 + cb + 4];
    float a[4] = {av.x, av.y, av.z, av.w};
    float w[8] = {wv0.x, wv0.y, wv0.z, wv0.w, wv1.x, wv1.y, wv1.z, wv1.w};
    #pragma unroll
    for (int r = 0; r < 4; ++r)
      #pragma unroll
      for (int j = 0; j < 8; ++j) acc[r][j] += a[r] * w[j];
  }
  float4 cb0 = *(const float4*)(Cb + cb);
  float4 cb1 = *(const float4*)(Cb + cb + 4);
  float cbv[8] = {cb0.x, cb0.y, cb0.z, cb0.w, cb1.x, cb1.y, cb1.z, cb1.w};
  float scv[8], shv[8];
  if (PASS == 2) {
    #pragma unroll
    for (int j = 0; j < 8; ++j) {
      scv[j] = bnp[128 + cb + j];
      shv[j] = bnp[192 + cb + j];
    }
  }
  float psum[8], psq[8];
  #pragma unroll
  for (int j = 0; j < 8; ++j) { psum[j] = 0.f; psq[j] = 0.f; }
  #pragma unroll
  for (int r = 0; r < 4; ++r) {
    int ei = e0 + rg * 4 + r;
    int sN = src[ei], dN = dst[ei];
    const float* dp = Dh + (size_t)sN * 64 + cb;
    const float* ep = Eh + (size_t)dN * 64 + cb;
    float4 d0 = *(const float4*)dp, d1 = *(const float4*)(dp + 4);
    float4 q0 = *(const float4*)ep, q1 = *(const float4*)(ep + 4);
    float dd[8] = {d0.x, d0.y, d0.z, d0.w, d1.x, d1.y, d1.z, d1.w};
    float qq[8] = {q0.x, q0.y, q0.z, q0.w, q1.x, q1.y, q1.z, q1.w};
    float ev[8];
    #pragma unroll
    for (int j = 0; j < 8; ++j) ev[j] = acc[r][j] + cbv[j] + dd[j] + qq[j];
    if (PASS == 1) {
      const float* bp = Bh + (size_t)sN * 64 + cb;
      float4 g0 = *(const float4*)bp, g1 = *(const float4*)(bp + 4);
      float gg[8] = {g0.x, g0.y, g0.z, g0.w, g1.x, g1.y, g1.z, g1.w};
      #pragma unroll
      for (int j = 0; j < 8; ++j) { psum[j] += ev[j]; psq[j] += ev[j] * ev[j]; }
      #pragma unroll
      for (int j = 0; j < 8; ++j) {
        float sg = 1.0f / (1.0f + __expf(-ev[j]));
        atomAddF(denb + (size_t)dN * 64 + cb + j, sg);
        atomAddF(numb + (size_t)dN * 64 + cb + j, sg * gg[j]);
      }
    } else {
      int row = rg * 4 + r;
      float ov[8];
      #pragma unroll
      for (int j = 0; j < 8; ++j) {
        int c = cb + j;
        float ein = esT[c * 160 + row + SK(c)];
        ov[j] = ein + fmaxf(ev[j] * scv[j] + shv[j], 0.f);
      }
      *(float4*)(eout + (size_t)ei * 64 + cb) = make_float4(ov[0], ov[1], ov[2], ov[3]);
      *(float4*)(eout + (size_t)ei * 64 + cb + 4) = make_float4(ov[4], ov[5], ov[6], ov[7]);
    }
  }
  if (PASS == 1) {
    __syncthreads();
    #pragma unroll
    for (int j = 0; j < 8; ++j) {
      lds[rg * 65 + cb + j] = psum[j];
      lds[2112 + rg * 65 + cb + j] = psq[j];
    }
    __syncthreads();
    if (t < 64) {
      float s = 0.f, q = 0.f;
      #pragma unroll
      for (int i = 0; i < 32; ++i) { s += lds[i * 65 + t]; q += lds[2112 + i * 65 + t]; }
      atomAddD(stats + 128 + t, (double)s);
      atomAddD(stats + 192 + t, (double)q);
    }
  }
}

__global__ __launch_bounds__(256) void k_node_upd1(float* __restrict__ hn,
    const float* __restrict__ numb, const float* __restrict__ denb, double* __restrict__ stats) {
  int t = threadIdx.x;
  float psum = 0.f, psq = 0.f;
  for (int i = blockIdx.x * 256 + t; i < NN * 64; i += gridDim.x * 256) {
    float v = hn[i] + numb[i] / (denb[i] + 1e-6f);
    hn[i] = v;
    psum += v; psq += v * v;
  }
  __shared__ float red[256];
  red[t] = psum; __syncthreads();
  if (t < 64) atomAddD(stats + t, (double)(red[t] + red[t + 64] + red[t + 128] + red[t + 192]));
  __syncthreads();
  red[t] = psq; __syncthreads();
  if (t < 64) atomAddD(stats + 64 + t, (double)(red[t] + red[t + 64] + red[t + 128] + red[t + 192]));
}

// ================= shared tail kernels =================

__global__ void k_bn_final(const double* __restrict__ stats,
    const float* __restrict__ hgam, const float* __restrict__ hbet,
    const float* __restrict__ egam, const float* __restrict__ ebet,
    float* __restrict__ bnp) {
  int t = threadIdx.x;
  if (t < 64) {
    double mu = stats[t] * (1.0 / NN);
    double var = stats[64 + t] * (1.0 / NN) - mu * mu;
    float sc = hgam[t] / sqrtf((float)var + 1e-5f);
    bnp[t] = sc;
    bnp[64 + t] = hbet[t] - (float)mu * sc;
  } else if (t < 128) {
    int c = t - 64;
    double mu = stats[128 + c] * (1.0 / NE);
    double var = stats[192 + c] * (1.0 / NE) - mu * mu;
    float sc = egam[c] / sqrtf((float)var + 1e-5f);
    bnp[128 + c] = sc;
    bnp[192 + c] = ebet[c] - (float)mu * sc;
  }
}

__global__ __launch_bounds__(256) void k_resid(float* __restrict__ x, const float* __restrict__ xh,
    const float* __restrict__ sc, const float* __restrict__ sh, int total4) {
  for (int i = blockIdx.x * 256 + threadIdx.x; i < total4; i += gridDim.x * 256) {
    int c = (i << 2) & 63;
    float4 hv = ((const float4*)xh)[i];
    float4 s4 = *(const float4*)(sc + c);
    float4 b4 = *(const float4*)(sh + c);
    float4 xv = ((float4*)x)[i];
    xv.x += fmaxf(hv.x * s4.x + b4.x, 0.f);
    xv.y += fmaxf(hv.y * s4.y + b4.y, 0.f);
    xv.z += fmaxf(hv.z * s4.z + b4.z, 0.f);
    xv.w += fmaxf(hv.w * s4.w + b4.w, 0.f);
    ((float4*)x)[i] = xv;
  }
}

__global__ __launch_bounds__(256) void k_readout(const float* __restrict__ h, const int* __restrict__ gid,
    float* __restrict__ hg, float* __restrict__ counts) {
  int t = threadIdx.x;
  int c = t & 63;
  int ro = t >> 6;
  int nbase = blockIdx.x * 64;
  float sum = 0.f, cnt = 0.f;
  int curg = -1;
  #pragma unroll 1
  for (int i = 0; i < 16; ++i) {
    int n = nbase + ro + i * 4;
    if (n >= NN) break;
    int g = gid[n];
    if (g != curg) {
      if (curg >= 0) {
        atomAddF(&hg[curg * 64 + c], sum);
        if (c == 0) atomAddF(&counts[curg], cnt);
      }
      curg = g; sum = 0.f; cnt = 0.f;
    }
    sum += h[(size_t)n * 64 + c];
    cnt += 1.f;
  }
  if (curg >= 0) {
    atomAddF(&hg[curg * 64 + c], sum);
    if (c == 0) atomAddF(&counts[curg], cnt);
  }
}

__global__ __launch_bounds__(256) void k_mlp(const float* __restrict__ hg, const float* __restrict__ counts,
    const float* __restrict__ state,
    const float* __restrict__ w1, const float* __restrict__ b1,
    const float* __restrict__ w2, const float* __restrict__ b2,
    const float* __restrict__ w3, const float* __restrict__ b3,
    float* __restrict__ out) {
  __shared__ float x0[16][68];
  __shared__ float x1[16][256];
  __shared__ float x2[16][256];
  int t = threadIdx.x;
  for (int idx = t; idx < 16 * 68; idx += 256) {
    int g = idx / 68, c = idx % 68;
    x0[g][c] = (c < 64) ? hg[g * 64 + c] / counts[g] : state[g * 4 + (c - 64)];
  }
  __syncthreads();
  {
    float acc[16];
    float bb = b1[t];
    #pragma unroll
    for (int g = 0; g < 16; ++g) acc[g] = bb;
    for (int k = 0; k < 68; ++k) {
      float w = w1[k * 256 + t];
      #pragma unroll
      for (int g = 0; g < 16; ++g) acc[g] += x0[g][k] * w;
    }
    #pragma unroll
    for (int g = 0; g < 16; ++g) x1[g][t] = fmaxf(acc[g], 0.f);
  }
  __syncthreads();
  {
    float acc[16];
    float bb = b2[t];
    #pragma unroll
    for (int g = 0; g < 16; ++g) acc[g] = bb;
    for (int k = 0; k < 256; ++k) {
      float w = w2[k * 256 + t];
      #pragma unroll
      for (int g = 0; g < 16; ++g) acc[g] += x1[g][k] * w;
    }
    #pragma unroll
    for (int g = 0; g < 16; ++g) x2[g][t] = fmaxf(acc[g], 0.f);
  }
  __syncthreads();
  if (t < 32) {
    int g = t >> 1, o = t & 1;
    float acc = b3[o];
    for (int k = 0; k < 256; ++k) acc += x2[g][k] * w3[k * 2 + o];
    out[g * 2 + o] = tanhf(acc);
  }
}

extern "C" void kernel_launch(void* const* d_in, const int* in_sizes, int n_in,
                              void* d_out, int out_size, void* d_ws, size_t ws_size,
                              hipStream_t stream) {
  const float* state   = (const float*)d_in[0];
  const float* h_feat  = (const float*)d_in[1];
  const float* e_feat  = (const float*)d_in[2];
  const int*   src     = (const int*)d_in[3];
  const int*   dst     = (const int*)d_in[4];
  const int*   gid     = (const int*)d_in[5];
  const float* emb_h_w = (const float*)d_in[6];
  const float* emb_h_b = (const float*)d_in[7];
  const float* emb_e_w = (const float*)d_in[8];
  const float* emb_e_b = (const float*)d_in[9];
  const float* A_w = (const float*)d_in[10];
  const float* A_b = (const float*)d_in[11];
  const float* B_w = (const float*)d_in[12];
  const float* B_b = (const float*)d_in[13];
  const float* C_w = (const float*)d_in[14];
  const float* C_b = (const float*)d_in[15];
  const float* D_w = (const float*)d_in[16];
  const float* D_b = (const float*)d_in[17];
  const float* E_w = (const float*)d_in[18];
  const float* E_b = (const float*)d_in[19];
  const float* bn_h_g = (const float*)d_in[20];
  const float* bn_h_b = (const float*)d_in[21];
  const float* bn_e_g = (const float*)d_in[22];
  const float* bn_e_b = (const float*)d_in[23];
  const float* l1_w = (const float*)d_in[24];
  const float* l1_b = (const float*)d_in[25];
  const float* l2_w = (const float*)d_in[26];
  const float* l2_b = (const float*)d_in[27];
  const float* l3_w = (const float*)d_in[28];
  const float* l3_b = (const float*)d_in[29];

  float* wsp = (float*)d_ws;

  // CSR-path layout (float units)
  const size_t F_H = (size_t)NN * 64;           // 3.2M
  const size_t F_E = (size_t)NE * 64;           // 25.6M
  size_t off = 0;
  float* h   = wsp + off; off += F_H;
  float* e   = wsp + off; off += F_E;
  float* Ah  = wsp + off; off += F_H;
  float* Bh  = wsp + off; off += F_H;
  float* Dh  = wsp + off; off += F_H;
  float* Eh  = wsp + off; off += F_H;
  __half* eh16 = (__half*)(wsp + off); off += F_E / 2;   // NE*64 halves
  int* perm   = (int*)(wsp + off); off += NE;
  int* srcp   = (int*)(wsp + off); off += NE;
  int* offs   = (int*)(wsp + off); off += NN + 4;        // 50004 (keeps even count)
  int* deg    = (int*)(wsp + off); off += NN;
  int* cursor = (int*)(wsp + off); off += NN;
  double* stats = (double*)(wsp + off); off += 512;      // 256 doubles
  float* bnp    = wsp + off; off += 256;
  float* hg     = wsp + off; off += 1024;
  float* counts = wsp + off; off += 16;
  const size_t needCSR = off * sizeof(float);

  if (ws_size >= needCSR) {
    // ---------- CSR path ----------
    k_embed_h<<<(NN * 16 + 255) / 256, 256, 0, stream>>>(h_feat, emb_h_w, emb_h_b, h);
    k_embed_e<<<(NE * 16 + 255) / 256, 256, 0, stream>>>(e_feat, emb_e_w, emb_e_b, e);
    // CSR build (once per call)
    k_zero<<<64, 256, 0, stream>>>((float4*)deg, NN / 4);
    k_deg<<<(NE + 255) / 256, 256, 0, stream>>>(dst, deg);
    k_scan<<<1, 1024, 0, stream>>>(deg, offs, cursor);
    k_scatter<<<(NE + 255) / 256, 256, 0, stream>>>(dst, src, cursor, perm, srcp);
    for (int l = 0; l < 3; ++l) {
      k_zero<<<1, 256, 0, stream>>>((float4*)stats, 128);
      k_node_gemm<<<(NN + 127) / 128, 256, 0, stream>>>(h,
          A_w + l * 4096, B_w + l * 4096, D_w + l * 4096, E_w + l * 4096,
          A_b + l * 64, B_b + l * 64, D_b + l * 64, E_b + l * 64, Ah);
      k_edge_csr<<<NE / 128, 256, 0, stream>>>(e, C_w + l * 4096, C_b + l * 64,
          src, dst, Dh, Eh, eh16, stats);
      k_agg<<<(NN + 15) / 16, 256, 0, stream>>>(offs, perm, srcp, eh16, Bh, Ah, stats);
      k_bn_final<<<1, 128, 0, stream>>>(stats, bn_h_g + l * 64, bn_h_b + l * 64,
          bn_e_g + l * 64, bn_e_b + l * 64, bnp);
      k_eresid<<<(NE * 8 + 255) / 256, 256, 0, stream>>>(e, eh16, bnp);
      k_resid<<<512, 256, 0, stream>>>(h, Ah, bnp, bnp + 64, NN * 16);
    }
    k_zero<<<2, 256, 0, stream>>>((float4*)hg, (1024 + 16) / 4);
    k_readout<<<(NN + 63) / 64, 256, 0, stream>>>(h, gid, hg, counts);
    k_mlp<<<1, 256, 0, stream>>>(hg, counts, state,
        l1_w, l1_b, l2_w, l2_b, l3_w, l3_b, (float*)d_out);
    return;
  }

  // ---------- fallback path (round-2 known-good layout) ----------
  const size_t needFB = ((size_t)NN * 64 * 7 + (size_t)NE * 64 + 4096) * sizeof(float);
  if (ws_size < needFB) return;
  {
    float*  fh     = wsp;
    float*  fe     = fh + F_H;
    float*  fAh    = fe + F_E;
    float*  fBh    = fAh + F_H;
    float*  fDh    = fBh + F_H;
    float*  fEh    = fDh + F_H;
    float*  numb   = fEh + F_H;
    float*  denb   = numb + F_H;
    double* fstats = (double*)(denb + F_H);
    float*  fbnp   = (float*)(fstats + 256);
    float*  fhg    = fbnp + 256;
    float*  fcounts= fhg + 1024;

    k_embed_h<<<(NN * 16 + 255) / 256, 256, 0, stream>>>(h_feat, emb_h_w, emb_h_b, fh);
    k_embed_e<<<(NE * 16 + 255) / 256, 256, 0, stream>>>(e_feat, emb_e_w, emb_e_b, fe);
    for (int l = 0; l < 3; ++l) {
      k_zero<<<2048, 256, 0, stream>>>((float4*)numb, (2 * NN * 64 + 512) / 4);
      k_node_gemm<<<(NN + 127) / 128, 256, 0, stream>>>(fh,
          A_w + l * 4096, B_w + l * 4096, D_w + l * 4096, E_w + l * 4096,
          A_b + l * 64, B_b + l * 64, D_b + l * 64, E_b + l * 64, fAh);
      k_edge<1><<<NE / 128, 256, 0, stream>>>(fe, C_w + l * 4096, C_b + l * 64, src, dst,
          fBh, fDh, fEh, numb, denb, fstats, nullptr, nullptr);
      k_node_upd1<<<1024, 256, 0, stream>>>(fAh, numb, denb, fstats);
      k_bn_final<<<1, 128, 0, stream>>>(fstats, bn_h_g + l * 64, bn_h_b + l * 64,
          bn_e_g + l * 64, bn_e_b + l * 64, fbnp);
      k_edge<2><<<NE / 128, 256, 0, stream>>>(fe, C_w + l * 4096, C_b + l * 64, src, dst,
          fBh, fDh, fEh, numb, denb, fstats, fbnp, fe);
      k_resid<<<512, 256, 0, stream>>>(fh, fAh, fbnp, fbnp + 64, NN * 16);
    }
    k_zero<<<2, 256, 0, stream>>>((float4*)fhg, (1024 + 16) / 4);
    k_readout<<<(NN + 63) / 64, 256, 0, stream>>>(fh, gid, fhg, fcounts);
    k_mlp<<<1, 256, 0, stream>>>(fhg, fcounts, state,
        l1_w, l1_b, l2_w, l2_b, l3_w, l3_b, (float*)d_out);
  }
}

// Round 5
// 972.322 us; speedup vs baseline: 4.8524x; 1.2295x over previous
//
#include <hip/hip_runtime.h>
#include <hip/hip_fp16.h>
#include <math.h>
#include <string.h>

#define NN 50000
#define NE 400000

#define SK(k) ((((k) >> 2) & 7) << 2)

__device__ __forceinline__ void atomAddF(float* p, float v) { unsafeAtomicAdd(p, v); }
__device__ __forceinline__ void atomAddD(double* p, double v) { unsafeAtomicAdd(p, v); }
__device__ __forceinline__ int atomAddI(int* p, int v) { return atomicAdd(p, v); }

__device__ __forceinline__ float2 up2h(unsigned v) {
  __half2 h; memcpy(&h, &v, 4); return __half22float2(h);
}
__device__ __forceinline__ unsigned pk2h(float a, float b) {
  __half2 h = __floats2half2_rn(a, b);
  unsigned v; memcpy(&v, &h, 4); return v;
}

// ---------------- zero fill ----------------
__global__ __launch_bounds__(256) void k_zero(float4* __restrict__ p, int n4) {
  int i = blockIdx.x * 256 + threadIdx.x;
  int s = gridDim.x * 256;
  for (; i < n4; i += s) p[i] = make_float4(0.f, 0.f, 0.f, 0.f);
}

// ---------------- embeddings ----------------
__global__ __launch_bounds__(256) void k_embed_h(const float* __restrict__ hf,
    const float* __restrict__ w, const float* __restrict__ b, float* __restrict__ h) {
  int i = blockIdx.x * 256 + threadIdx.x;
  if (i >= NN * 16) return;
  int n = i >> 4, c0 = (i & 15) * 4;
  float4 acc = *(const float4*)(b + c0);
  const float* row = hf + n * 6;
  #pragma unroll
  for (int k = 0; k < 6; ++k) {
    float x = row[k];
    const float4 wv = *(const float4*)(w + k * 64 + c0);
    acc.x += x * wv.x; acc.y += x * wv.y; acc.z += x * wv.z; acc.w += x * wv.w;
  }
  ((float4*)h)[i] = acc;
}

// e in CSR order from raw pairs ef2 (already CSR-permuted)
__global__ __launch_bounds__(256) void k_embed_e(const float* __restrict__ ef2,
    const float* __restrict__ w, const float* __restrict__ b, float* __restrict__ e) {
  int i = blockIdx.x * 256 + threadIdx.x;
  if (i >= NE * 16) return;
  int p = i >> 4, c0 = (i & 15) * 4;
  float2 raw = ((const float2*)ef2)[p];
  float r0 = 1.0f / raw.x;
  float r1 = 1.0f / raw.y;
  float4 acc = *(const float4*)(b + c0);
  const float4 w0 = *(const float4*)(w + c0);
  const float4 w1 = *(const float4*)(w + 64 + c0);
  acc.x += r0 * w0.x + r1 * w1.x;
  acc.y += r0 * w0.y + r1 * w1.y;
  acc.z += r0 * w0.z + r1 * w1.z;
  acc.w += r0 * w0.w + r1 * w1.w;
  ((float4*)e)[i] = acc;
}

// ---------------- CSR build ----------------
__global__ __launch_bounds__(256) void k_deg(const int* __restrict__ dst, int* __restrict__ deg) {
  int i = blockIdx.x * 256 + threadIdx.x;
  if (i < NE) atomAddI(&deg[dst[i]], 1);
}

// degcur: in = degrees, out = cursor (== exclusive prefix). Also zeroes stats.
__global__ __launch_bounds__(1024) void k_scan(int* __restrict__ degcur,
    int* __restrict__ offs, double* __restrict__ stats) {
  __shared__ int wsum[16];
  int t = threadIdx.x;
  int lane = t & 63, w = t >> 6;
  if (t < 256) stats[t] = 0.0;
  int carry = 0;
  for (int base = 0; base < NN; base += 1024) {
    int i = base + t;
    int v = (i < NN) ? degcur[i] : 0;
    int x = v;
    #pragma unroll
    for (int off = 1; off < 64; off <<= 1) {
      int y = __shfl_up(x, off);
      if (lane >= off) x += y;
    }
    if (lane == 63) wsum[w] = x;
    __syncthreads();
    if (w == 0 && lane < 16) {
      int s = wsum[lane];
      #pragma unroll
      for (int off = 1; off < 16; off <<= 1) {
        int y = __shfl_up(s, off);
        if (lane >= off) s += y;
      }
      wsum[lane] = s;
    }
    __syncthreads();
    int wbase = (w > 0) ? wsum[w - 1] : 0;
    int total = wsum[15];
    int excl = carry + wbase + x - v;
    if (i < NN) { offs[i] = excl; degcur[i] = excl; }
    carry += total;
    __syncthreads();
  }
  if (t == 0) offs[NN] = carry;
}

__global__ __launch_bounds__(256) void k_scatter(const int* __restrict__ dst,
    const int* __restrict__ src, const float* __restrict__ e_feat,
    int* __restrict__ cursor,
    int* __restrict__ srcp, int* __restrict__ dstp, float* __restrict__ ef2) {
  int i = blockIdx.x * 256 + threadIdx.x;
  if (i < NE) {
    int d = dst[i];
    int p = atomAddI(&cursor[d], 1);
    srcp[p] = src[i];
    dstp[p] = d;
    ((float2*)ef2)[p] = ((const float2*)e_feat)[i];
  }
}

// ---------------- node GEMM: out[y] = h @ W_y + b_y for y in {A,B,D,E} ----------------
__global__ __launch_bounds__(256) void k_node_gemm(const float* __restrict__ h,
    const float* __restrict__ w0, const float* __restrict__ w1,
    const float* __restrict__ w2, const float* __restrict__ w3,
    const float* __restrict__ b0, const float* __restrict__ b1,
    const float* __restrict__ b2, const float* __restrict__ b3,
    float* __restrict__ out) {
  __shared__ float lds[64 * 160 + 64 * 64];
  float* hsT = lds;
  float* wsh = lds + 64 * 160;
  int t = threadIdx.x;
  int n0 = blockIdx.x * 128;
  #pragma unroll
  for (int i = 0; i < 8; ++i) {
    int f = (t + i * 256) * 4;
    int r = f >> 6;
    int k = f & 63;
    int n = n0 + r;
    float4 v = make_float4(0.f, 0.f, 0.f, 0.f);
    if (n < NN) v = *(const float4*)(h + (size_t)n * 64 + k);
    int s = SK(k);
    hsT[(k + 0) * 160 + r + s] = v.x;
    hsT[(k + 1) * 160 + r + s] = v.y;
    hsT[(k + 2) * 160 + r + s] = v.z;
    hsT[(k + 3) * 160 + r + s] = v.w;
  }
  int cg = t & 7, rg = t >> 3;
  int cb = cg * 8;
  #pragma unroll 1
  for (int y = 0; y < 4; ++y) {
    const float* W = (y == 0) ? w0 : (y == 1) ? w1 : (y == 2) ? w2 : w3;
    const float* B = (y == 0) ? b0 : (y == 1) ? b1 : (y == 2) ? b2 : b3;
    __syncthreads();
    #pragma unroll
    for (int i = 0; i < 4; ++i)
      ((float4*)wsh)[t + i * 256] = ((const float4*)W)[t + i * 256];
    __syncthreads();
    float acc[4][8];
    #pragma unroll
    for (int r = 0; r < 4; ++r)
      #pragma unroll
      for (int j = 0; j < 8; ++j) acc[r][j] = 0.f;
    #pragma unroll 8
    for (int k = 0; k < 64; ++k) {
      float4 av = *(const float4*)&hsT[k * 160 + SK(k) + rg * 4];
      float4 wv0 = *(const float4*)&wsh[k * 64 + cb];
      float4 wv1 = *(const float4*)&wsh[k * 64 + cb + 4];
      float a[4] = {av.x, av.y, av.z, av.w};
      float w[8] = {wv0.x, wv0.y, wv0.z, wv0.w, wv1.x, wv1.y, wv1.z, wv1.w};
      #pragma unroll
      for (int r = 0; r < 4; ++r)
        #pragma unroll
        for (int j = 0; j < 8; ++j) acc[r][j] += a[r] * w[j];
    }
    float4 bv0 = *(const float4*)(B + cb);
    float4 bv1 = *(const float4*)(B + cb + 4);
    float* oy = out + (size_t)y * NN * 64;
    #pragma unroll
    for (int r = 0; r < 4; ++r) {
      int n = n0 + rg * 4 + r;
      if (n < NN) {
        *(float4*)(oy + (size_t)n * 64 + cb) =
            make_float4(acc[r][0] + bv0.x, acc[r][1] + bv0.y,
                        acc[r][2] + bv0.z, acc[r][3] + bv0.w);
        *(float4*)(oy + (size_t)n * 64 + cb + 4) =
            make_float4(acc[r][4] + bv1.x, acc[r][5] + bv1.y,
                        acc[r][6] + bv1.z, acc[r][7] + bv1.w);
      }
    }
  }
}

// ---------------- fused edge kernel (CSR order) ----------------
// MODE==1: during staging apply previous layer's e-residual:
//          e_new = e + relu(eh16_prev*sc + sh), written back to e.
// Then: e_hat = e_new@Cw+Cb + Dh[srcp] + Eh[dstp]; store fp16 e_hat;
// ESTATS: accumulate e-BN stats (skipped for the last layer).
template <int MODE, int ESTATS>
__global__ __launch_bounds__(256) void k_edge_f(float* __restrict__ e,
    __half* __restrict__ eh16,
    const float* __restrict__ Cw, const float* __restrict__ Cb,
    const int* __restrict__ srcp, const int* __restrict__ dstp,
    const float* __restrict__ Dh, const float* __restrict__ Eh,
    const float* __restrict__ bnp, double* __restrict__ stats) {
  __shared__ float lds[64 * 160 + 64 * 64];
  float* esT = lds;
  float* cw = lds + 64 * 160;
  int t = threadIdx.x;
  int e0 = blockIdx.x * 128;
  {
    const float4* s4 = (const float4*)Cw;
    float4* d4 = (float4*)cw;
    #pragma unroll
    for (int i = 0; i < 4; ++i) d4[t + i * 256] = s4[t + i * 256];
  }
  #pragma unroll
  for (int i = 0; i < 8; ++i) {
    int f = (t + i * 256) * 4;
    int r = f >> 6;
    int k = f & 63;
    size_t idx = (size_t)(e0 + r) * 64 + k;
    float4 v = *(const float4*)(e + idx);
    if (MODE == 1) {
      uint2 hh = *(const uint2*)(eh16 + idx);
      float2 fa = up2h(hh.x), fb = up2h(hh.y);
      float4 sc = *(const float4*)(bnp + 128 + k);
      float4 sh = *(const float4*)(bnp + 192 + k);
      v.x += fmaxf(fa.x * sc.x + sh.x, 0.f);
      v.y += fmaxf(fa.y * sc.y + sh.y, 0.f);
      v.z += fmaxf(fb.x * sc.z + sh.z, 0.f);
      v.w += fmaxf(fb.y * sc.w + sh.w, 0.f);
      *(float4*)(e + idx) = v;
    }
    int s = SK(k);
    esT[(k + 0) * 160 + r + s] = v.x;
    esT[(k + 1) * 160 + r + s] = v.y;
    esT[(k + 2) * 160 + r + s] = v.z;
    esT[(k + 3) * 160 + r + s] = v.w;
  }
  __syncthreads();
  int cg = t & 7, rg = t >> 3;
  int cb = cg * 8;
  float acc[4][8];
  #pragma unroll
  for (int r = 0; r < 4; ++r)
    #pragma unroll
    for (int j = 0; j < 8; ++j) acc[r][j] = 0.f;
  #pragma unroll 8
  for (int k = 0; k < 64; ++k) {
    float4 av = *(const float4*)&esT[k * 160 + SK(k) + rg * 4];
    float4 wv0 = *(const float4*)&cw[k * 64 + cb];
    float4 wv1 = *(const float4*)&cw[k * 64 + cb + 4];
    float a[4] = {av.x, av.y, av.z, av.w};
    float w[8] = {wv0.x, wv0.y, wv0.z, wv0.w, wv1.x, wv1.y, wv1.z, wv1.w};
    #pragma unroll
    for (int r = 0; r < 4; ++r)
      #pragma unroll
      for (int j = 0; j < 8; ++j) acc[r][j] += a[r] * w[j];
  }
  float4 cb0 = *(const float4*)(Cb + cb);
  float4 cb1 = *(const float4*)(Cb + cb + 4);
  float cbv[8] = {cb0.x, cb0.y, cb0.z, cb0.w, cb1.x, cb1.y, cb1.z, cb1.w};
  float psum[8], psq[8];
  #pragma unroll
  for (int j = 0; j < 8; ++j) { psum[j] = 0.f; psq[j] = 0.f; }
  #pragma unroll
  for (int r = 0; r < 4; ++r) {
    int p = e0 + rg * 4 + r;
    int sN = srcp[p], dN = dstp[p];
    const float* dp = Dh + (size_t)sN * 64 + cb;
    const float* ep = Eh + (size_t)dN * 64 + cb;
    float4 d0 = *(const float4*)dp, d1 = *(const float4*)(dp + 4);
    float4 q0 = *(const float4*)ep, q1 = *(const float4*)(ep + 4);
    float dd[8] = {d0.x, d0.y, d0.z, d0.w, d1.x, d1.y, d1.z, d1.w};
    float qq[8] = {q0.x, q0.y, q0.z, q0.w, q1.x, q1.y, q1.z, q1.w};
    float ev[8];
    #pragma unroll
    for (int j = 0; j < 8; ++j) {
      float v = acc[r][j] + cbv[j] + dd[j] + qq[j];
      ev[j] = v;
      if (ESTATS) { psum[j] += v; psq[j] += v * v; }
    }
    uint4 u;
    u.x = pk2h(ev[0], ev[1]);
    u.y = pk2h(ev[2], ev[3]);
    u.z = pk2h(ev[4], ev[5]);
    u.w = pk2h(ev[6], ev[7]);
    *(uint4*)(eh16 + (size_t)p * 64 + cb) = u;
  }
  if (ESTATS) {
    __syncthreads();
    #pragma unroll
    for (int j = 0; j < 8; ++j) {
      lds[rg * 65 + cb + j] = psum[j];
      lds[2112 + rg * 65 + cb + j] = psq[j];
    }
    __syncthreads();
    if (t < 64) {
      float s = 0.f, q = 0.f;
      #pragma unroll
      for (int i = 0; i < 32; ++i) { s += lds[i * 65 + t]; q += lds[2112 + i * 65 + t]; }
      atomAddD(stats + 128 + t, (double)s);
      atomAddD(stats + 192 + t, (double)q);
    }
  }
}

// ---------------- aggregation (streaming eh16) + h update + h BN stats ----------------
__global__ __launch_bounds__(256) void k_agg(const int* __restrict__ offs,
    const int* __restrict__ srcp, const __half* __restrict__ eh16,
    const float* __restrict__ Bh, float* __restrict__ Ah, double* __restrict__ stats) {
  int t = threadIdx.x;
  int c = t & 63;
  int g = t >> 6;
  float psum = 0.f, psq = 0.f;
  #pragma unroll 1
  for (int sub = 0; sub < 4; ++sub) {
    int n = blockIdx.x * 16 + g * 4 + sub;
    if (n < NN) {
      int i0 = offs[n], i1 = offs[n + 1];
      float num = 0.f, den = 0.f;
      int i = i0;
      #pragma unroll 1
      for (; i + 1 < i1; i += 2) {
        float x0 = __half2float(eh16[(size_t)i * 64 + c]);
        float x1 = __half2float(eh16[(size_t)(i + 1) * 64 + c]);
        int s0 = srcp[i], s1 = srcp[i + 1];
        float b0 = Bh[(size_t)s0 * 64 + c];
        float b1 = Bh[(size_t)s1 * 64 + c];
        float g0 = 1.0f / (1.0f + __expf(-x0));
        float g1 = 1.0f / (1.0f + __expf(-x1));
        num += g0 * b0 + g1 * b1;
        den += g0 + g1;
      }
      if (i < i1) {
        float x0 = __half2float(eh16[(size_t)i * 64 + c]);
        int s0 = srcp[i];
        float b0 = Bh[(size_t)s0 * 64 + c];
        float g0 = 1.0f / (1.0f + __expf(-x0));
        num += g0 * b0;
        den += g0;
      }
      float v = Ah[(size_t)n * 64 + c] + num / (den + 1e-6f);
      Ah[(size_t)n * 64 + c] = v;
      psum += v; psq += v * v;
    }
  }
  __shared__ float red[256];
  red[t] = psum; __syncthreads();
  if (t < 64) atomAddD(stats + t, (double)(red[t] + red[t + 64] + red[t + 128] + red[t + 192]));
  __syncthreads();
  red[t] = psq; __syncthreads();
  if (t < 64) atomAddD(stats + 64 + t, (double)(red[t] + red[t + 64] + red[t + 128] + red[t + 192]));
}

// ---------------- finalize BN scale/shift; zero stats for next layer ----------------
__global__ void k_bn_final(double* __restrict__ stats,
    const float* __restrict__ hgam, const float* __restrict__ hbet,
    const float* __restrict__ egam, const float* __restrict__ ebet,
    float* __restrict__ bnp) {
  int t = threadIdx.x;
  if (t < 64) {
    double mu = stats[t] * (1.0 / NN);
    double var = stats[64 + t] * (1.0 / NN) - mu * mu;
    float sc = hgam[t] / sqrtf((float)var + 1e-5f);
    bnp[t] = sc;
    bnp[64 + t] = hbet[t] - (float)mu * sc;
  } else if (t < 128) {
    int c = t - 64;
    double mu = stats[128 + c] * (1.0 / NE);
    double var = stats[192 + c] * (1.0 / NE) - mu * mu;
    float sc = egam[c] / sqrtf((float)var + 1e-5f);
    bnp[128 + c] = sc;
    bnp[192 + c] = ebet[c] - (float)mu * sc;
  }
  __syncthreads();
  stats[t] = 0.0;
  stats[t + 128] = 0.0;
}

// ---------------- h = h + relu(Ah*sc + sh) ----------------
__global__ __launch_bounds__(256) void k_resid(float* __restrict__ x, const float* __restrict__ xh,
    const float* __restrict__ sc, const float* __restrict__ sh, int total4) {
  for (int i = blockIdx.x * 256 + threadIdx.x; i < total4; i += gridDim.x * 256) {
    int c = (i << 2) & 63;
    float4 hv = ((const float4*)xh)[i];
    float4 s4 = *(const float4*)(sc + c);
    float4 b4 = *(const float4*)(sh + c);
    float4 xv = ((float4*)x)[i];
    xv.x += fmaxf(hv.x * s4.x + b4.x, 0.f);
    xv.y += fmaxf(hv.y * s4.y + b4.y, 0.f);
    xv.z += fmaxf(hv.z * s4.z + b4.z, 0.f);
    xv.w += fmaxf(hv.w * s4.w + b4.w, 0.f);
    ((float4*)x)[i] = xv;
  }
}

// ---------------- per-graph mean readout (graph_ids sorted) ----------------
__global__ __launch_bounds__(256) void k_readout(const float* __restrict__ h, const int* __restrict__ gid,
    float* __restrict__ hg, float* __restrict__ counts) {
  int t = threadIdx.x;
  int c = t & 63;
  int ro = t >> 6;
  int nbase = blockIdx.x * 64;
  float sum = 0.f, cnt = 0.f;
  int curg = -1;
  #pragma unroll 1
  for (int i = 0; i < 16; ++i) {
    int n = nbase + ro + i * 4;
    if (n >= NN) break;
    int g = gid[n];
    if (g != curg) {
      if (curg >= 0) {
        atomAddF(&hg[curg * 64 + c], sum);
        if (c == 0) atomAddF(&counts[curg], cnt);
      }
      curg = g; sum = 0.f; cnt = 0.f;
    }
    sum += h[(size_t)n * 64 + c];
    cnt += 1.f;
  }
  if (curg >= 0) {
    atomAddF(&hg[curg * 64 + c], sum);
    if (c == 0) atomAddF(&counts[curg], cnt);
  }
}

// ---------------- final MLP (16 graphs), one block ----------------
__global__ __launch_bounds__(256) void k_mlp(const float* __restrict__ hg, const float* __restrict__ counts,
    const float* __restrict__ state,
    const float* __restrict__ w1, const float* __restrict__ b1,
    const float* __restrict__ w2, const float* __restrict__ b2,
    const float* __restrict__ w3, const float* __restrict__ b3,
    float* __restrict__ out) {
  __shared__ float x0[16][68];
  __shared__ float x1[16][256];
  __shared__ float x2[16][256];
  int t = threadIdx.x;
  for (int idx = t; idx < 16 * 68; idx += 256) {
    int g = idx / 68, c = idx % 68;
    x0[g][c] = (c < 64) ? hg[g * 64 + c] / counts[g] : state[g * 4 + (c - 64)];
  }
  __syncthreads();
  {
    float acc[16];
    float bb = b1[t];
    #pragma unroll
    for (int g = 0; g < 16; ++g) acc[g] = bb;
    for (int k = 0; k < 68; ++k) {
      float w = w1[k * 256 + t];
      #pragma unroll
      for (int g = 0; g < 16; ++g) acc[g] += x0[g][k] * w;
    }
    #pragma unroll
    for (int g = 0; g < 16; ++g) x1[g][t] = fmaxf(acc[g], 0.f);
  }
  __syncthreads();
  {
    float acc[16];
    float bb = b2[t];
    #pragma unroll
    for (int g = 0; g < 16; ++g) acc[g] = bb;
    for (int k = 0; k < 256; ++k) {
      float w = w2[k * 256 + t];
      #pragma unroll
      for (int g = 0; g < 16; ++g) acc[g] += x1[g][k] * w;
    }
    #pragma unroll
    for (int g = 0; g < 16; ++g) x2[g][t] = fmaxf(acc[g], 0.f);
  }
  __syncthreads();
  if (t < 32) {
    int g = t >> 1, o = t & 1;
    float acc = b3[o];
    for (int k = 0; k < 256; ++k) acc += x2[g][k] * w3[k * 2 + o];
    out[g * 2 + o] = tanhf(acc);
  }
}

extern "C" void kernel_launch(void* const* d_in, const int* in_sizes, int n_in,
                              void* d_out, int out_size, void* d_ws, size_t ws_size,
                              hipStream_t stream) {
  const float* state   = (const float*)d_in[0];
  const float* h_feat  = (const float*)d_in[1];
  const float* e_feat  = (const float*)d_in[2];
  const int*   src     = (const int*)d_in[3];
  const int*   dst     = (const int*)d_in[4];
  const int*   gid     = (const int*)d_in[5];
  const float* emb_h_w = (const float*)d_in[6];
  const float* emb_h_b = (const float*)d_in[7];
  const float* emb_e_w = (const float*)d_in[8];
  const float* emb_e_b = (const float*)d_in[9];
  const float* A_w = (const float*)d_in[10];
  const float* A_b = (const float*)d_in[11];
  const float* B_w = (const float*)d_in[12];
  const float* B_b = (const float*)d_in[13];
  const float* C_w = (const float*)d_in[14];
  const float* C_b = (const float*)d_in[15];
  const float* D_w = (const float*)d_in[16];
  const float* D_b = (const float*)d_in[17];
  const float* E_w = (const float*)d_in[18];
  const float* E_b = (const float*)d_in[19];
  const float* bn_h_g = (const float*)d_in[20];
  const float* bn_h_b = (const float*)d_in[21];
  const float* bn_e_g = (const float*)d_in[22];
  const float* bn_e_b = (const float*)d_in[23];
  const float* l1_w = (const float*)d_in[24];
  const float* l1_b = (const float*)d_in[25];
  const float* l2_w = (const float*)d_in[26];
  const float* l2_b = (const float*)d_in[27];
  const float* l3_w = (const float*)d_in[28];
  const float* l3_b = (const float*)d_in[29];

  float* wsp = (float*)d_ws;

  const size_t F_H = (size_t)NN * 64;
  const size_t F_E = (size_t)NE * 64;
  size_t off = 0;
  float* h     = wsp + off; off += F_H;
  float* e     = wsp + off; off += F_E;
  float* Ah    = wsp + off; off += F_H;
  float* Bh    = wsp + off; off += F_H;
  float* Dh    = wsp + off; off += F_H;
  float* Eh    = wsp + off; off += F_H;
  __half* eh16 = (__half*)(wsp + off); off += F_E / 2;   // NE*64 halves
  float* ef2   = (float*)eh16;                           // overlay: raw CSR-ordered e_feat pairs
  int* srcp    = (int*)(wsp + off); off += NE;
  int* dstp    = (int*)(wsp + off); off += NE;
  int* offs    = (int*)(wsp + off); off += NN + 4;
  int* degcur  = (int*)(wsp + off); off += NN;           // deg, then cursor
  double* stats = (double*)(wsp + off); off += 512;      // 256 doubles
  float* bnp    = wsp + off; off += 256;
  float* hg     = wsp + off; off += 1024;
  float* counts = wsp + off; off += 16;
  const size_t need = off * sizeof(float);
  if (ws_size < need) return;

  // CSR build + embeds
  k_zero<<<64, 256, 0, stream>>>((float4*)degcur, NN / 4);
  k_deg<<<(NE + 255) / 256, 256, 0, stream>>>(dst, degcur);
  k_scan<<<1, 1024, 0, stream>>>(degcur, offs, stats);
  k_scatter<<<(NE + 255) / 256, 256, 0, stream>>>(dst, src, e_feat, degcur, srcp, dstp, ef2);
  k_embed_e<<<(NE * 16 + 255) / 256, 256, 0, stream>>>(ef2, emb_e_w, emb_e_b, e);
  k_embed_h<<<(NN * 16 + 255) / 256, 256, 0, stream>>>(h_feat, emb_h_w, emb_h_b, h);

  for (int l = 0; l < 3; ++l) {
    k_node_gemm<<<(NN + 127) / 128, 256, 0, stream>>>(h,
        A_w + l * 4096, B_w + l * 4096, D_w + l * 4096, E_w + l * 4096,
        A_b + l * 64, B_b + l * 64, D_b + l * 64, E_b + l * 64, Ah);
    if (l == 0)
      k_edge_f<0, 1><<<NE / 128, 256, 0, stream>>>(e, eh16, C_w, C_b,
          srcp, dstp, Dh, Eh, bnp, stats);
    else if (l == 1)
      k_edge_f<1, 1><<<NE / 128, 256, 0, stream>>>(e, eh16, C_w + 4096, C_b + 64,
          srcp, dstp, Dh, Eh, bnp, stats);
    else
      k_edge_f<1, 0><<<NE / 128, 256, 0, stream>>>(e, eh16, C_w + 8192, C_b + 128,
          srcp, dstp, Dh, Eh, bnp, stats);
    k_agg<<<(NN + 15) / 16, 256, 0, stream>>>(offs, srcp, eh16, Bh, Ah, stats);
    k_bn_final<<<1, 128, 0, stream>>>(stats, bn_h_g + l * 64, bn_h_b + l * 64,
        bn_e_g + l * 64, bn_e_b + l * 64, bnp);
    k_resid<<<512, 256, 0, stream>>>(h, Ah, bnp, bnp + 64, NN * 16);
  }
  k_zero<<<2, 256, 0, stream>>>((float4*)hg, (1024 + 16) / 4);
  k_readout<<<(NN + 63) / 64, 256, 0, stream>>>(h, gid, hg, counts);
  k_mlp<<<1, 256, 0, stream>>>(hg, counts, state,
      l1_w, l1_b, l2_w, l2_b, l3_w, l3_b, (float*)d_out);
}